// Round 3
// baseline (1051.324 us; speedup 1.0000x reference)
//
#include <hip/hip_runtime.h>
#include <cstdint>
#include <cstddef>

#define NSEG 64
#define NCH 16
#define ALPHA 1.0f
#define BETA 1.0f
#define GAMMA 0.001f
#define DELTA_D 1.5f
// DELTA_V == 0.0

#define TPB 256
#define KQ 4            // quads (float4) per thread per channel
#define WQ (TPB * KQ)   // quads per block = 1024

// ws layout (floats):
//   [0,1024)      gsums[c][l]   (c-major, 16x64)
//   [1024,1088)   gcounts[64]   (as unsigned)
//   [1088,1152)   gper[64]
//   [1152,2176)   gmeans[c][l]
//   [2176,2180)   scalars: [0]=K, [1]=partial(ext+nrm)
//   byte offset 16384: segs[P] (uchar), if ws_size permits

__global__ __launch_bounds__(256) void init_kernel(float* __restrict__ ws) {
    int i = blockIdx.x * 256 + threadIdx.x;
    if (i < 4096) ws[i] = 0.f;
}

// Pass 1 (merged seg + sums): each thread owns KQ quads for ALL channels.
// Phase A: compute segment ids once -> registers (+ global segs for pass2,
// + counts). Phase B: sweep channels; embd loads depend only on induction
// variables (no data-dependent branch gates any load).
__global__ __launch_bounds__(256) void pass1_kernel(
    const float* __restrict__ embd, const int* __restrict__ trgt,
    const int* __restrict__ mask, unsigned char* __restrict__ segs,
    float* __restrict__ gsums, unsigned int* __restrict__ gcounts, int P)
{
    __shared__ float lsums[NCH * NSEG];
    __shared__ unsigned int lcounts[NSEG];
    for (int i = threadIdx.x; i < NCH * NSEG; i += TPB) lsums[i] = 0.f;
    if (threadIdx.x < NSEG) lcounts[threadIdx.x] = 0u;
    __syncthreads();

    const int P4 = P >> 2;
    const int t = threadIdx.x;

    if (P4 > 0) {
        const size_t base = (size_t)blockIdx.x * WQ;
        const int4* __restrict__ trgt4 = (const int4*)trgt;
        const int4* __restrict__ mask4 = (const int4*)mask;
        const float4* __restrict__ embd4 = (const float4*)embd;

        size_t q[KQ];
        bool val[KQ];
        unsigned int pk[KQ];

        #pragma unroll
        for (int k = 0; k < KQ; ++k) {
            size_t qq = base + (size_t)k * TPB + t;
            val[k] = qq < (size_t)P4;
            if (!val[k]) qq = (size_t)P4 - 1;   // clamp: loads always in-bounds
            q[k] = qq;
        }

        // Phase A: segment ids -> registers; counts; segs store for pass2
        #pragma unroll
        for (int k = 0; k < KQ; ++k) {
            int4 tt = trgt4[q[k]];
            int4 mm = mask4[q[k]];
            int s0 = (mm.x > 0) ? tt.x : 0;
            int s1 = (mm.y > 0) ? tt.y : 0;
            int s2 = (mm.z > 0) ? tt.z : 0;
            int s3 = (mm.w > 0) ? tt.w : 0;
            if (!val[k]) { s0 = s1 = s2 = s3 = 0; }
            pk[k] = (unsigned)s0 | ((unsigned)s1 << 8) |
                    ((unsigned)s2 << 16) | ((unsigned)s3 << 24);
            if (val[k] && segs) {
                uchar4 u;
                u.x = (unsigned char)s0; u.y = (unsigned char)s1;
                u.z = (unsigned char)s2; u.w = (unsigned char)s3;
                ((uchar4*)segs)[q[k]] = u;
            }
            if (s0) atomicAdd(&lcounts[s0], 1u);
            if (s1) atomicAdd(&lcounts[s1], 1u);
            if (s2) atomicAdd(&lcounts[s2], 1u);
            if (s3) atomicAdd(&lcounts[s3], 1u);
        }

        // Phase B: channel sweep. Loads are branch-free and induction-only.
        #pragma unroll 2
        for (int c = 0; c < NCH; ++c) {
            float4 v[KQ];
            #pragma unroll
            for (int k = 0; k < KQ; ++k)
                v[k] = embd4[(size_t)c * P4 + q[k]];
            float* __restrict__ row = &lsums[c * NSEG];
            #pragma unroll
            for (int k = 0; k < KQ; ++k) {
                int s0 = pk[k] & 255;
                int s1 = (pk[k] >> 8) & 255;
                int s2 = (pk[k] >> 16) & 255;
                int s3 = pk[k] >> 24;
                if (s0) atomicAdd(&row[s0], v[k].x);
                if (s1) atomicAdd(&row[s1], v[k].y);
                if (s2) atomicAdd(&row[s2], v[k].z);
                if (s3) atomicAdd(&row[s3], v[k].w);
            }
        }
    }

    // scalar tail over P%4 voxels (empty for this problem)
    for (size_t p = (size_t)P4 * 4 + (size_t)blockIdx.x * TPB + t;
         p < (size_t)P; p += (size_t)gridDim.x * TPB) {
        int s = (mask[p] > 0) ? trgt[p] : 0;
        if (segs) segs[p] = (unsigned char)s;
        if (s) {
            atomicAdd(&lcounts[s], 1u);
            for (int c = 0; c < NCH; ++c)
                atomicAdd(&lsums[c * NSEG + s], embd[(size_t)c * P + p]);
        }
    }

    __syncthreads();
    for (int i = threadIdx.x; i < NCH * NSEG; i += TPB) {
        float v = lsums[i];
        if (v != 0.f) atomicAdd(&gsums[i], v);
    }
    if (threadIdx.x < NSEG) {
        unsigned int v = lcounts[threadIdx.x];
        if (v) atomicAdd(&gcounts[threadIdx.x], v);
    }
}

__global__ __launch_bounds__(256) void mid_kernel(
    const float* __restrict__ gsums, const unsigned int* __restrict__ gcounts,
    float* __restrict__ gmeans, float* __restrict__ scalars)
{
    __shared__ float smeans[NCH * NSEG];
    __shared__ float scnt[NSEG];
    __shared__ float s_ext, s_nrm;
    int tid = threadIdx.x;
    if (tid == 0) { s_ext = 0.f; s_nrm = 0.f; }
    if (tid < NSEG) scnt[tid] = (float)gcounts[tid];
    __syncthreads();
    for (int i = tid; i < NCH * NSEG; i += 256) {
        int l = i & (NSEG - 1);
        float mean = gsums[i] / fmaxf(scnt[l], 1.f);
        smeans[i] = mean;
        gmeans[i] = mean;
    }
    __syncthreads();
    if (tid < NSEG) {
        int l = tid;
        if (l != 0 && scnt[l] > 0.f) {
            float a = 0.f;
            #pragma unroll
            for (int c = 0; c < NCH; ++c) a += fabsf(smeans[c * NSEG + l]);
            atomicAdd(&s_nrm, a);
        }
    }
    float eacc = 0.f;
    for (int q = tid; q < NSEG * NSEG; q += 256) {
        int l1 = q >> 6, l2 = q & 63;
        if (l1 != l2 && l1 != 0 && l2 != 0 && scnt[l1] > 0.f && scnt[l2] > 0.f) {
            float d = 0.f;
            #pragma unroll
            for (int c = 0; c < NCH; ++c)
                d += fabsf(smeans[c * NSEG + l1] - smeans[c * NSEG + l2]);
            float mm = fmaxf(2.f * DELTA_D - d, 0.f);
            eacc += mm * mm;
        }
    }
    if (eacc != 0.f) atomicAdd(&s_ext, eacc);
    __syncthreads();
    if (tid == 0) {
        float K = 0.f;
        for (int l = 1; l < NSEG; ++l) if (scnt[l] > 0.f) K += 1.f;
        scalars[0] = K;
        scalars[1] = BETA * s_ext / fmaxf(1.f, K * (K - 1.f))
                   + GAMMA * s_nrm / fmaxf(1.f, K);
    }
}

// Pass 2: per-voxel L1 accumulators live in registers across the channel
// sweep; squared hinge applied once at the end. Same branch-free load
// structure as pass1.
__global__ __launch_bounds__(256) void pass2_kernel(
    const float* __restrict__ embd, const unsigned char* __restrict__ segs,
    const int* __restrict__ trgt, const int* __restrict__ mask,
    const float* __restrict__ gmeans, float* __restrict__ gper, int P)
{
    __shared__ float lmeans[NCH * NSEG];
    __shared__ float lper[NSEG];
    for (int i = threadIdx.x; i < NCH * NSEG; i += TPB) lmeans[i] = gmeans[i];
    if (threadIdx.x < NSEG) lper[threadIdx.x] = 0.f;
    __syncthreads();

    const int P4 = P >> 2;
    const int t = threadIdx.x;

    if (P4 > 0) {
        const size_t base = (size_t)blockIdx.x * WQ;
        const float4* __restrict__ embd4 = (const float4*)embd;

        size_t q[KQ];
        bool val[KQ];
        unsigned int pk[KQ];

        #pragma unroll
        for (int k = 0; k < KQ; ++k) {
            size_t qq = base + (size_t)k * TPB + t;
            val[k] = qq < (size_t)P4;
            if (!val[k]) qq = (size_t)P4 - 1;
            q[k] = qq;
        }

        #pragma unroll
        for (int k = 0; k < KQ; ++k) {
            unsigned int pp;
            if (segs) {
                uchar4 u = ((const uchar4*)segs)[q[k]];
                pp = (unsigned)u.x | ((unsigned)u.y << 8) |
                     ((unsigned)u.z << 16) | ((unsigned)u.w << 24);
            } else {
                int4 tt = ((const int4*)trgt)[q[k]];
                int4 mm = ((const int4*)mask)[q[k]];
                int s0 = (mm.x > 0) ? tt.x : 0;
                int s1 = (mm.y > 0) ? tt.y : 0;
                int s2 = (mm.z > 0) ? tt.z : 0;
                int s3 = (mm.w > 0) ? tt.w : 0;
                pp = (unsigned)s0 | ((unsigned)s1 << 8) |
                     ((unsigned)s2 << 16) | ((unsigned)s3 << 24);
            }
            if (!val[k]) pp = 0;
            pk[k] = pp;
        }

        float4 acc[KQ];
        #pragma unroll
        for (int k = 0; k < KQ; ++k) acc[k] = make_float4(0.f, 0.f, 0.f, 0.f);

        #pragma unroll 2
        for (int c = 0; c < NCH; ++c) {
            float4 v[KQ];
            #pragma unroll
            for (int k = 0; k < KQ; ++k)
                v[k] = embd4[(size_t)c * P4 + q[k]];
            const float* __restrict__ row = &lmeans[c * NSEG];
            #pragma unroll
            for (int k = 0; k < KQ; ++k) {
                int s0 = pk[k] & 255;
                int s1 = (pk[k] >> 8) & 255;
                int s2 = (pk[k] >> 16) & 255;
                int s3 = pk[k] >> 24;
                acc[k].x += fabsf(v[k].x - row[s0]);
                acc[k].y += fabsf(v[k].y - row[s1]);
                acc[k].z += fabsf(v[k].z - row[s2]);
                acc[k].w += fabsf(v[k].w - row[s3]);
            }
        }

        #pragma unroll
        for (int k = 0; k < KQ; ++k) {
            int s0 = pk[k] & 255;
            int s1 = (pk[k] >> 8) & 255;
            int s2 = (pk[k] >> 16) & 255;
            int s3 = pk[k] >> 24;
            if (s0) { float h = fmaxf(acc[k].x, 0.f); atomicAdd(&lper[s0], h * h); }
            if (s1) { float h = fmaxf(acc[k].y, 0.f); atomicAdd(&lper[s1], h * h); }
            if (s2) { float h = fmaxf(acc[k].z, 0.f); atomicAdd(&lper[s2], h * h); }
            if (s3) { float h = fmaxf(acc[k].w, 0.f); atomicAdd(&lper[s3], h * h); }
        }
    }

    // scalar tail (empty for this problem)
    for (size_t p = (size_t)P4 * 4 + (size_t)blockIdx.x * TPB + t;
         p < (size_t)P; p += (size_t)gridDim.x * TPB) {
        int s = segs ? (int)segs[p] : ((mask[p] > 0) ? trgt[p] : 0);
        if (s) {
            float a = 0.f;
            for (int c = 0; c < NCH; ++c)
                a += fabsf(embd[(size_t)c * P + p] - lmeans[c * NSEG + s]);
            float h = fmaxf(a, 0.f);
            atomicAdd(&lper[s], h * h);
        }
    }

    __syncthreads();
    if (threadIdx.x < NSEG) {
        float v = lper[threadIdx.x];
        if (v != 0.f) atomicAdd(&gper[threadIdx.x], v);
    }
}

__global__ __launch_bounds__(64) void final_kernel(
    const float* __restrict__ gper, const unsigned int* __restrict__ gcounts,
    const float* __restrict__ scalars, float* __restrict__ out)
{
    int l = threadIdx.x;
    float cnt = (float)gcounts[l];
    bool present = (l != 0) && (cnt > 0.f);
    float v = present ? gper[l] / fmaxf(cnt, 1.f) : 0.f;
    #pragma unroll
    for (int off = 32; off > 0; off >>= 1) v += __shfl_down(v, off);
    if (l == 0) {
        float K = scalars[0];
        float loss_int = v / fmaxf(1.f, K);
        out[0] = ALPHA * loss_int + scalars[1];
    }
}

extern "C" void kernel_launch(void* const* d_in, const int* in_sizes, int n_in,
                              void* d_out, int out_size, void* d_ws, size_t ws_size,
                              hipStream_t stream) {
    const float* embd = (const float*)d_in[0];
    const int* trgt = (const int*)d_in[1];
    const int* mask = (const int*)d_in[2];
    const int P = in_sizes[1];  // 32*512*512

    float* ws = (float*)d_ws;
    float* gsums = ws;                                   // 1024
    unsigned int* gcounts = (unsigned int*)(ws + 1024);  // 64
    float* gper = ws + 1088;                             // 64
    float* gmeans = ws + 1152;                           // 1024
    float* scalars = ws + 2176;                          // 2

    unsigned char* segs = nullptr;
    const size_t seg_off = 16384;
    if (ws_size >= seg_off + (size_t)P) segs = (unsigned char*)d_ws + seg_off;

    const int P4 = P >> 2;
    int G = P4 > 0 ? (P4 + WQ - 1) / WQ : 1;   // 2048 for P = 32*512*512

    init_kernel<<<(4096 + 255) / 256, 256, 0, stream>>>(ws);
    pass1_kernel<<<G, 256, 0, stream>>>(embd, trgt, mask, segs, gsums, gcounts, P);
    mid_kernel<<<1, 256, 0, stream>>>(gsums, gcounts, gmeans, scalars);
    pass2_kernel<<<G, 256, 0, stream>>>(embd, segs, trgt, mask, gmeans, gper, P);
    final_kernel<<<1, 64, 0, stream>>>(gper, gcounts, scalars, (float*)d_out);
}